// Round 7
// baseline (442.102 us; speedup 1.0000x reference)
//
#include <hip/hip_runtime.h>
#include <hip/hip_bf16.h>

#define NN 8192
#define FIN 128
#define FOUT 64
#define ALPHA 0.2f
#define BM 64                // rows per attn block
#define CHUNK 128            // j-tile per pipeline stage
#define SPLIT 8              // j-range split factor (1024 j per block)
#define JSLICE (NN / SPLIT)
#define NCHUNK (JSLICE / CHUNK)   // 8
#define PROW (CHUNK + 8)     // 272B row stride: 4-bank skew
#define LOG2E 1.44269504f
#define MBROW (NN / 4)       // mask bytes per row (2048): 1 byte = 4 j bits

typedef __attribute__((ext_vector_type(8))) short short8;   // 8 bf16 (4 VGPRs)
typedef __attribute__((ext_vector_type(4))) float floatx4;

#if __has_builtin(__builtin_amdgcn_exp2f)
#define EXP2(x) __builtin_amdgcn_exp2f(x)
#else
#define EXP2(x) exp2f(x)
#endif

static __device__ __forceinline__ ushort f2bf(float f) {
    __hip_bfloat16 h = __float2bfloat16(f);
    return __builtin_bit_cast(ushort, h);
}

// K0: adj int32 -> nibble mask (1 byte per 4 j). PURE stream, no cross-lane:
// lane loads int4 (16B, its own 4 consecutive j), stores 1 byte (64B/wave-store).
// 2048 blocks x 256 thr; wave = one row; 32 iters of 4KB-per-wave reads.
// maskB[row][j/4] bit q = adj[row][j/4*4 + q] > 0.
__global__ __launch_bounds__(256) void adj_to_mask(const int* __restrict__ adj,
                                                   unsigned char* __restrict__ maskB) {
    const int t = threadIdx.x;
    const int lane = t & 63;
    const int wv = t >> 6;
    const int row = blockIdx.x * 4 + wv;
    const int4* __restrict__ ap = (const int4*)(adj + (size_t)row * NN) + lane;
    unsigned char* __restrict__ mp = maskB + (size_t)row * MBROW + lane;
    #pragma unroll 4
    for (int g = 0; g < NN / 256; ++g) {
        const int4 v = ap[g * 64];                 // adj[row][g*256 + lane*4 ..+3]
        const int nib = (v.x > 0 ? 1 : 0) | (v.y > 0 ? 2 : 0)
                      | (v.z > 0 ? 4 : 0) | (v.w > 0 ? 8 : 0);
        mp[g * 64] = (unsigned char)nib;           // byte lane-coalesced
    }
}

// K1: WhT[f][row] = bf16(x @ W); Wh1/Wh2 = (Wh @ a) * log2e  (fp32)
// grid NN/16 = 512 blocks x 256 thr. Wave: 4 rows, W reused across rows.
__global__ __launch_bounds__(256) void gat_proj(const float* __restrict__ x,
                                                const float* __restrict__ W,
                                                const float* __restrict__ a,
                                                ushort* __restrict__ WhT,
                                                float* __restrict__ Wh1,
                                                float* __restrict__ Wh2) {
    __shared__ float tile[16][FOUT + 1];

    const int t = threadIdx.x;
    const int f = t & 63;
    const int wvu = __builtin_amdgcn_readfirstlane(t >> 6);
    const int row0 = blockIdx.x * 16;
    const float af1 = a[f], af2 = a[FOUT + f];

    const float* __restrict__ xr = x + (size_t)(row0 + wvu * 4) * FIN;

    float accv[4] = {0.f, 0.f, 0.f, 0.f};
    #pragma unroll
    for (int k = 0; k < FIN; k += 4) {
        const float w0 = W[(k + 0) * FOUT + f];
        const float w1 = W[(k + 1) * FOUT + f];
        const float w2 = W[(k + 2) * FOUT + f];
        const float w3 = W[(k + 3) * FOUT + f];
        #pragma unroll
        for (int r = 0; r < 4; ++r) {
            const float4 xv = *(const float4*)(xr + (size_t)r * FIN + k);
            accv[r] = fmaf(xv.x, w0, fmaf(xv.y, w1, fmaf(xv.z, w2, fmaf(xv.w, w3, accv[r]))));
        }
    }

    #pragma unroll
    for (int r = 0; r < 4; ++r) {
        tile[wvu * 4 + r][f] = accv[r];
        float s1 = accv[r] * af1;
        float s2 = accv[r] * af2;
        #pragma unroll
        for (int off = 32; off; off >>= 1) {
            s1 += __shfl_xor(s1, off, 64);
            s2 += __shfl_xor(s2, off, 64);
        }
        if (f == 0) {
            const int row = row0 + wvu * 4 + r;
            Wh1[row] = s1 * LOG2E;      // pre-fold log2e: leaky is +scale-invariant
            Wh2[row] = s2 * LOG2E;
        }
    }
    __syncthreads();

    const int r = t & 15;
    const int fh = t >> 4;
    #pragma unroll
    for (int p = 0; p < 4; ++p) {
        const int ff = p * 16 + fh;
        WhT[(size_t)ff * NN + row0 + r] = f2bf(tile[r][ff]);
    }
}

// K2: partial masked-softmax num/den via bf16 MFMA, byte-mask input.
// grid (NN/BM)*SPLIT = 1024 blocks x 256 thr (4 waves), ~4 blocks/CU.
// Statically-unrolled even/odd 2-deep pipeline (NO dynamic reg indexing).
__global__ __launch_bounds__(256) void gat_attn_part(const unsigned char* __restrict__ maskB,
                                                     const ushort* __restrict__ WhT,
                                                     const float* __restrict__ Wh1,
                                                     const float* __restrict__ Wh2,
                                                     float* __restrict__ pnum,
                                                     float* __restrict__ pden) {
    __shared__ __align__(16) ushort P[2][BM][PROW];   // 34.8 KB

    const int t = threadIdx.x;
    const int lane = t & 63;
    const int wvu = __builtin_amdgcn_readfirstlane(t >> 6);
    const int slice = blockIdx.x & (SPLIT - 1);
    const int row0 = (blockIdx.x / SPLIT) * BM;
    const int j0 = slice * JSLICE;
    const int ln = lane & 15;
    const int quad = lane >> 4;
    const int jg = lane & 31;      // j-group within chunk (4 j each)
    const int rh = lane >> 5;      // row half (0/1) of wave's 16 score rows
    const int rbase = wvu * 16;

    float wh1r[8];
    #pragma unroll
    for (int rr = 0; rr < 8; ++rr)
        wh1r[rr] = Wh1[row0 + rbase + rh * 8 + rr];

    // lane's mask byte for chunk c, row rr: mrowp[rr*MBROW + c*32]
    const unsigned char* __restrict__ mrowp =
        maskB + (size_t)(row0 + rbase + rh * 8) * MBROW + j0 / 4 + jg;
    const ushort* __restrict__ bbase =
        WhT + (size_t)(wvu * 16 + ln) * NN + j0 + quad * 8;

    unsigned int mE[8], mO[8];
    float4 wh2E, wh2O;
    short8 bfE[4], bfO[4];
    float den[8];
    #pragma unroll
    for (int rr = 0; rr < 8; ++rr) den[rr] = 0.f;
    floatx4 acc[4];
    #pragma unroll
    for (int mt = 0; mt < 4; ++mt) acc[mt] = (floatx4){0.f, 0.f, 0.f, 0.f};

#define LOADM(c, M, WH2)                                                   \
    {                                                                      \
        WH2 = *(const float4*)(Wh2 + j0 + (c) * CHUNK + jg * 4);           \
        _Pragma("unroll")                                                  \
        for (int rr = 0; rr < 8; ++rr)                                     \
            M[rr] = mrowp[(size_t)rr * MBROW + (c) * (CHUNK / 4)];         \
    }
#define LOADB(c, BF)                                                       \
    {                                                                      \
        _Pragma("unroll")                                                  \
        for (int k0 = 0; k0 < 4; ++k0)                                     \
            BF[k0] = *(const short8*)(bbase + (c) * CHUNK + k0 * 32);      \
    }
#define SCORES(M, WH2, b)                                                  \
    {                                                                      \
        _Pragma("unroll")                                                  \
        for (int rr = 0; rr < 8; ++rr) {                                   \
            const float w1 = wh1r[rr];                                     \
            float s0 = w1 + WH2.x, s1 = w1 + WH2.y,                        \
                  s2 = w1 + WH2.z, s3 = w1 + WH2.w;                        \
            s0 = fmaxf(s0, ALPHA * s0); s1 = fmaxf(s1, ALPHA * s1);        \
            s2 = fmaxf(s2, ALPHA * s2); s3 = fmaxf(s3, ALPHA * s3);        \
            float p0 = EXP2(s0), p1 = EXP2(s1),                            \
                  p2 = EXP2(s2), p3 = EXP2(s3);                            \
            const unsigned int mm = M[rr];                                 \
            p0 = (mm & 1u) ? p0 : 0.f;                                     \
            p1 = (mm & 2u) ? p1 : 0.f;                                     \
            p2 = (mm & 4u) ? p2 : 0.f;                                     \
            p3 = (mm & 8u) ? p3 : 0.f;                                     \
            den[rr] += (p0 + p1) + (p2 + p3);                              \
            ushort4 pk = make_ushort4(f2bf(p0), f2bf(p1), f2bf(p2), f2bf(p3)); \
            *(ushort4*)&P[b][rbase + rh * 8 + rr][jg * 4] = pk;            \
        }                                                                  \
    }
#define MFMA(b, BF)                                                        \
    {                                                                      \
        _Pragma("unroll")                                                  \
        for (int mt = 0; mt < 4; ++mt) {                                   \
            const ushort* Arow = &P[b][mt * 16 + ln][quad * 8];            \
            _Pragma("unroll")                                              \
            for (int k0 = 0; k0 < 4; ++k0) {                               \
                short8 af = *(const short8*)(Arow + k0 * 32);              \
                acc[mt] = __builtin_amdgcn_mfma_f32_16x16x32_bf16(af, BF[k0], acc[mt], 0, 0, 0); \
            }                                                              \
        }                                                                  \
    }

    // prologue
    LOADM(0, mE, wh2E); LOADB(0, bfE);
    LOADM(1, mO, wh2O); LOADB(1, bfO);
    SCORES(mE, wh2E, 0);          // chunk 0 -> buf0 (consumes E)
    LOADM(2, mE, wh2E);           // refill E
    __syncthreads();

    #pragma unroll
    for (int c = 0; c < NCHUNK; c += 2) {
        // even chunk c: MFMA from buf0 with bfE
        MFMA(0, bfE);
        if (c + 2 < NCHUNK) LOADB(c + 2, bfE);
        SCORES(mO, wh2O, 1);                       // chunk c+1 -> buf1
        if (c + 3 < NCHUNK) LOADM(c + 3, mO, wh2O);
        __syncthreads();
        // odd chunk c+1: MFMA from buf1 with bfO
        MFMA(1, bfO);
        if (c + 3 < NCHUNK) LOADB(c + 3, bfO);
        if (c + 2 < NCHUNK) SCORES(mE, wh2E, 0);   // chunk c+2 -> buf0
        if (c + 4 < NCHUNK) LOADM(c + 4, mE, wh2E);
        __syncthreads();
    }
#undef LOADM
#undef LOADB
#undef SCORES
#undef MFMA

    // partial den: reduce across the 32-lane half (lanes of one rh share rows)
    #pragma unroll
    for (int rr = 0; rr < 8; ++rr) {
        float d = den[rr];
        #pragma unroll
        for (int off = 16; off; off >>= 1) d += __shfl_xor(d, off, 64);
        if (jg == 0)
            pden[(size_t)slice * NN + row0 + rbase + rh * 8 + rr] = d;
    }

    // partial num: D[m = quad*4 + r][n = ln] per m-tile (verified C/D layout)
    #pragma unroll
    for (int mt = 0; mt < 4; ++mt) {
        #pragma unroll
        for (int r = 0; r < 4; ++r) {
            const int i = mt * 16 + quad * 4 + r;
            pnum[((size_t)slice * NN + row0 + i) * FOUT + wvu * 16 + ln] = acc[mt][r];
        }
    }
}

// K3: combine SPLIT partials, normalize, ELU. grid NN*FOUT/256.
__global__ __launch_bounds__(256) void gat_combine(const float* __restrict__ pnum,
                                                   const float* __restrict__ pden,
                                                   float* __restrict__ out) {
    const int idx = blockIdx.x * 256 + threadIdx.x;
    const int row = idx >> 6;
    float num = 0.f, den = 0.f;
    #pragma unroll
    for (int s = 0; s < SPLIT; ++s) {
        num += pnum[(size_t)s * NN * FOUT + idx];
        den += pden[(size_t)s * NN + row];
    }
    float o = num / den;
    o = (o > 0.f) ? o : (__expf(o) - 1.f);
    out[idx] = o;
}

extern "C" void kernel_launch(void* const* d_in, const int* in_sizes, int n_in,
                              void* d_out, int out_size, void* d_ws, size_t ws_size,
                              hipStream_t stream) {
    const float* x   = (const float*)d_in[0];   // [N, FIN]
    const int*   adj = (const int*)  d_in[1];   // [N, N]
    const float* W   = (const float*)d_in[2];   // [FIN, FOUT]
    const float* a   = (const float*)d_in[3];   // [2*FOUT, 1]
    float* out = (float*)d_out;                 // [N, FOUT]

    // ws: WhT bf16 [64][8192] (1MB) | Wh1 f32 [N] | Wh2 f32 [N]
    //   | pnum f32 [SPLIT][N][FOUT] (16MB) | pden f32 [SPLIT][N] (256KB)
    //   | maskB u8 [N][N/4] (16.8MB)
    ushort* WhT = (ushort*)d_ws;
    float* Wh1 = (float*)(WhT + (size_t)FOUT * NN);
    float* Wh2 = Wh1 + NN;
    float* pnum = Wh2 + NN;
    float* pden = pnum + (size_t)SPLIT * NN * FOUT;
    unsigned char* maskB = (unsigned char*)(pden + (size_t)SPLIT * NN);

    adj_to_mask<<<NN / 4, 256, 0, stream>>>(adj, maskB);
    gat_proj<<<NN / 16, 256, 0, stream>>>(x, W, a, WhT, Wh1, Wh2);
    gat_attn_part<<<(NN / BM) * SPLIT, 256, 0, stream>>>(maskB, WhT, Wh1, Wh2, pnum, pden);
    gat_combine<<<NN * FOUT / 256, 256, 0, stream>>>(pnum, pden, out);
}